// Round 2
// baseline (3186.311 us; speedup 1.0000x reference)
//
#include <hip/hip_runtime.h>

static constexpr int FEAT = 128;
static constexpr int SCAN_B = 256;

__device__ __forceinline__ float4 f4add(float4 a, float4 b) {
  return make_float4(a.x + b.x, a.y + b.y, a.z + b.z, a.w + b.w);
}

// ---------------- CSR build ----------------

__global__ void k_zero_int(int* __restrict__ p, int n) {
  int i = blockIdx.x * blockDim.x + threadIdx.x;
  if (i < n) p[i] = 0;
}

__global__ void k_degree(const int* __restrict__ dst, int E, int* __restrict__ deg) {
  int e = blockIdx.x * blockDim.x + threadIdx.x;
  if (e < E) atomicAdd(&deg[dst[e]], 1);
}

__global__ void k_scan_local(const int* __restrict__ deg, int N,
                             int* __restrict__ off, int* __restrict__ aux) {
  __shared__ int s[SCAN_B];
  int t = threadIdx.x;
  int i = blockIdx.x * SCAN_B + t;
  int v = (i < N) ? deg[i] : 0;
  s[t] = v;
  __syncthreads();
  for (int d = 1; d < SCAN_B; d <<= 1) {
    int add = (t >= d) ? s[t - d] : 0;
    __syncthreads();
    s[t] += add;
    __syncthreads();
  }
  if (i < N) off[i] = s[t] - v;            // exclusive within block
  if (t == SCAN_B - 1) aux[blockIdx.x] = s[t];
}

__global__ void k_scan_aux(int* __restrict__ aux, int nb) {
  __shared__ int s[SCAN_B];
  int t = threadIdx.x;
  int v = (t < nb) ? aux[t] : 0;
  s[t] = v;
  __syncthreads();
  for (int d = 1; d < SCAN_B; d <<= 1) {
    int add = (t >= d) ? s[t - d] : 0;
    __syncthreads();
    s[t] += add;
    __syncthreads();
  }
  if (t < nb) aux[t] = s[t] - v;           // exclusive block offsets
}

__global__ void k_finish(int* __restrict__ off, const int* __restrict__ aux,
                         const int* __restrict__ deg, float* __restrict__ dinv,
                         int* __restrict__ cursor, int N, int E) {
  int i = blockIdx.x * blockDim.x + threadIdx.x;
  if (i < N) {
    int o = off[i] + aux[i >> 8];          // blockDim == SCAN_B == 256
    off[i] = o;
    cursor[i] = o;
    dinv[i] = rsqrtf((float)(deg[i] + 1)); // degree over A+I
  }
  if (i == 0) off[N] = E;
}

__global__ void k_fill(const int* __restrict__ src, const int* __restrict__ dst, int E,
                       int* __restrict__ cursor, int* __restrict__ csr) {
  int e = blockIdx.x * blockDim.x + threadIdx.x;
  if (e < E) {
    int p = atomicAdd(&cursor[dst[e]], 1);
    csr[p] = src[e];
  }
}

// ---------------- dense GEMM: Y[r] = dinv[r] * (X[r] @ W) ----------------
// 64x128 C-tile per block, Kc=32 double-buffered, per-thread 4 rows x 8 cols.
// Per k-step per lane: 3 ds_read_b128 (36 cyc/wave) vs 32 FMA (64 cyc) -> VALU-bound.
__global__ __launch_bounds__(256) void k_gemm_scaled(
    const float* __restrict__ X, const float* __restrict__ W,
    const float* __restrict__ dinv, float* __restrict__ Y, int N) {
  constexpr int KC = 32;
  constexpr int LDA = 68;   // [KC][64 rows] stride: 68*4B = 272B, 16B-aligned rows
  constexpr int LDB = 132;  // [KC][128 cols] stride: 132*4B, 16B-aligned rows
  __shared__ float At[2][KC * LDA];
  __shared__ float Bt[2][KC * LDB];

  const int t = threadIdx.x;
  const int tx = t & 15;            // col group: cols tx*8..tx*8+7
  const int ty = t >> 4;            // row group: rows ty*4..ty*4+3
  const int r0 = blockIdx.x * 64;

  // staging maps
  const int ar = t >> 2;            // 0..63  row
  const int ak = (t & 3) * 4;       // 0,4,8,12 (and +16)
  const int bk = t >> 4;            // 0..15  (and +16)
  const int bc = (t & 15) * 8;      // 0..120

  const float* xrow = X + (size_t)(r0 + ar < N ? r0 + ar : N - 1) * FEAT;
  const float* wrow = W + (size_t)bk * FEAT + bc;

  float4 aP0, aP1, bP0, bP1, bP2, bP3;
  // prefetch chunk 0
  aP0 = *(const float4*)(xrow + ak);
  aP1 = *(const float4*)(xrow + ak + 16);
  bP0 = *(const float4*)(wrow);
  bP1 = *(const float4*)(wrow + 4);
  bP2 = *(const float4*)(wrow + 16 * FEAT);
  bP3 = *(const float4*)(wrow + 16 * FEAT + 4);
  {
    float* a = At[0];
    a[(ak + 0) * LDA + ar] = aP0.x; a[(ak + 1) * LDA + ar] = aP0.y;
    a[(ak + 2) * LDA + ar] = aP0.z; a[(ak + 3) * LDA + ar] = aP0.w;
    a[(ak + 16) * LDA + ar] = aP1.x; a[(ak + 17) * LDA + ar] = aP1.y;
    a[(ak + 18) * LDA + ar] = aP1.z; a[(ak + 19) * LDA + ar] = aP1.w;
    float* b = Bt[0];
    *(float4*)&b[bk * LDB + bc] = bP0;
    *(float4*)&b[bk * LDB + bc + 4] = bP1;
    *(float4*)&b[(bk + 16) * LDB + bc] = bP2;
    *(float4*)&b[(bk + 16) * LDB + bc + 4] = bP3;
  }
  __syncthreads();

  float acc[4][8];
#pragma unroll
  for (int i = 0; i < 4; i++)
#pragma unroll
    for (int j = 0; j < 8; j++) acc[i][j] = 0.f;

  const int NT = FEAT / KC;  // 4 chunks
#pragma unroll
  for (int kt = 0; kt < NT; kt++) {
    const int cur = kt & 1;
    if (kt + 1 < NT) {
      const int k0 = (kt + 1) * KC;
      aP0 = *(const float4*)(xrow + k0 + ak);
      aP1 = *(const float4*)(xrow + k0 + ak + 16);
      bP0 = *(const float4*)(wrow + (size_t)k0 * FEAT);
      bP1 = *(const float4*)(wrow + (size_t)k0 * FEAT + 4);
      bP2 = *(const float4*)(wrow + (size_t)(k0 + 16) * FEAT);
      bP3 = *(const float4*)(wrow + (size_t)(k0 + 16) * FEAT + 4);
    }
    const float* a = At[cur];
    const float* b = Bt[cur];
#pragma unroll
    for (int kk = 0; kk < KC; kk++) {
      float4 av = *(const float4*)&a[kk * LDA + ty * 4];
      float4 bv0 = *(const float4*)&b[kk * LDB + tx * 8];
      float4 bv1 = *(const float4*)&b[kk * LDB + tx * 8 + 4];
      float ax[4] = {av.x, av.y, av.z, av.w};
      float bx[8] = {bv0.x, bv0.y, bv0.z, bv0.w, bv1.x, bv1.y, bv1.z, bv1.w};
#pragma unroll
      for (int i = 0; i < 4; i++)
#pragma unroll
        for (int j = 0; j < 8; j++) acc[i][j] += ax[i] * bx[j];
    }
    if (kt + 1 < NT) {
      const int nxt = cur ^ 1;
      __syncthreads();  // everyone done reading buf nxt (from iter kt-1)
      float* a2 = At[nxt];
      a2[(ak + 0) * LDA + ar] = aP0.x; a2[(ak + 1) * LDA + ar] = aP0.y;
      a2[(ak + 2) * LDA + ar] = aP0.z; a2[(ak + 3) * LDA + ar] = aP0.w;
      a2[(ak + 16) * LDA + ar] = aP1.x; a2[(ak + 17) * LDA + ar] = aP1.y;
      a2[(ak + 18) * LDA + ar] = aP1.z; a2[(ak + 19) * LDA + ar] = aP1.w;
      float* b2 = Bt[nxt];
      *(float4*)&b2[bk * LDB + bc] = bP0;
      *(float4*)&b2[bk * LDB + bc + 4] = bP1;
      *(float4*)&b2[(bk + 16) * LDB + bc] = bP2;
      *(float4*)&b2[(bk + 16) * LDB + bc + 4] = bP3;
      __syncthreads();  // stores visible before next compute
    }
  }

  // epilogue: scale rows by dinv, store
#pragma unroll
  for (int i = 0; i < 4; i++) {
    const int r = r0 + ty * 4 + i;
    if (r >= N) continue;
    const float dn = dinv[r];
    float4 o0 = make_float4(acc[i][0] * dn, acc[i][1] * dn, acc[i][2] * dn, acc[i][3] * dn);
    float4 o1 = make_float4(acc[i][4] * dn, acc[i][5] * dn, acc[i][6] * dn, acc[i][7] * dn);
    float4* yp = (float4*)(Y + (size_t)r * FEAT + tx * 8);
    yp[0] = o0;
    yp[1] = o1;
  }
}

// ---------------- propagation ----------------
// h[n] = relu(dinv[n]*(sum_in xws[s] + xws[n]) + b), xws pre-scaled by dinv.
// 32 lanes x float4 per node, 8 nodes/block, edge loop unrolled x4 (4 gathers in flight).
__global__ __launch_bounds__(256) void k_prop(
    const float4* __restrict__ X4, const int* __restrict__ off,
    const int* __restrict__ csr, const float* __restrict__ dinv,
    const float4* __restrict__ bias4, float4* __restrict__ H4, int N) {
  const int node = blockIdx.x * 8 + (threadIdx.x >> 5);
  if (node >= N) return;
  const int j = threadIdx.x & 31;
  const int i0 = off[node], i1 = off[node + 1];
  float4 a0 = make_float4(0.f, 0.f, 0.f, 0.f), a1 = a0, a2 = a0, a3 = a0;
  int i = i0;
  for (; i + 4 <= i1; i += 4) {
    const int s0 = csr[i], s1 = csr[i + 1], s2 = csr[i + 2], s3 = csr[i + 3];
    float4 v0 = X4[(size_t)s0 * 32 + j];
    float4 v1 = X4[(size_t)s1 * 32 + j];
    float4 v2 = X4[(size_t)s2 * 32 + j];
    float4 v3 = X4[(size_t)s3 * 32 + j];
    a0 = f4add(a0, v0); a1 = f4add(a1, v1); a2 = f4add(a2, v2); a3 = f4add(a3, v3);
  }
  for (; i < i1; i++) a0 = f4add(a0, X4[(size_t)csr[i] * 32 + j]);
  float4 acc = f4add(f4add(a0, a1), f4add(a2, a3));
  acc = f4add(acc, X4[(size_t)node * 32 + j]);
  const float dn = dinv[node];
  const float4 b = bias4[j];
  float4 r;
  r.x = fmaxf(dn * acc.x + b.x, 0.f);
  r.y = fmaxf(dn * acc.y + b.y, 0.f);
  r.z = fmaxf(dn * acc.z + b.z, 0.f);
  r.w = fmaxf(dn * acc.w + b.w, 0.f);
  H4[(size_t)node * 32 + j] = r;
}

// ---------------- pooling: per-graph mean over sorted batch ----------------
__device__ __forceinline__ int lower_bound(const int* __restrict__ a, int n, int v) {
  int lo = 0, hi = n;
  while (lo < hi) { int m = (lo + hi) >> 1; if (a[m] < v) lo = m + 1; else hi = m; }
  return lo;
}

__global__ __launch_bounds__(256) void k_pool(
    const float4* __restrict__ H4, const int* __restrict__ batch,
    int N, float4* __restrict__ out4) {
  __shared__ float4 red[8][32];
  const int g = blockIdx.x;
  const int grp = threadIdx.x >> 5;
  const int j = threadIdx.x & 31;
  const int lo = lower_bound(batch, N, g);
  const int hi = lower_bound(batch, N, g + 1);
  float4 a = make_float4(0.f, 0.f, 0.f, 0.f);
  for (int r = lo + grp; r < hi; r += 8) a = f4add(a, H4[(size_t)r * 32 + j]);
  red[grp][j] = a;
  __syncthreads();
  if (grp == 0) {
    float4 s = red[0][j];
#pragma unroll
    for (int k = 1; k < 8; k++) s = f4add(s, red[k][j]);
    const int cnt = hi - lo;
    const float dn = 1.0f / (float)(cnt > 1 ? cnt : 1);
    out4[g * 32 + j] = make_float4(s.x * dn, s.y * dn, s.z * dn, s.w * dn);
  }
}

// ---------------- launch ----------------
extern "C" void kernel_launch(void* const* d_in, const int* in_sizes, int n_in,
                              void* d_out, int out_size, void* d_ws, size_t ws_size,
                              hipStream_t stream) {
  const float* x     = (const float*)d_in[0];
  const int*   ei    = (const int*)  d_in[1];
  const int*   batch = (const int*)  d_in[2];
  // d_in[3] = num_graphs scalar (derived from out_size instead)
  const float* W1    = (const float*)d_in[4];
  const float* b1    = (const float*)d_in[5];
  const float* W2    = (const float*)d_in[6];
  const float* b2    = (const float*)d_in[7];

  const int N = in_sizes[0] / FEAT;
  const int E = in_sizes[1] / 2;
  const int G = out_size / FEAT;
  const int* src = ei;
  const int* dst = ei + E;

  char* w = (char*)d_ws;
  float* xw   = (float*)w;  w += (size_t)N * FEAT * 4;
  float* h    = (float*)w;  w += (size_t)N * FEAT * 4;
  int*   deg  = (int*)w;    w += (size_t)N * 4;
  int*   off  = (int*)w;    w += ((size_t)(N + 1) * 4 + 15) & ~(size_t)15;
  int*   aux  = (int*)w;    w += 256 * 4;
  int*   curs = (int*)w;    w += (size_t)N * 4;
  int*   csr  = (int*)w;    w += (size_t)E * 4;
  float* dinv = (float*)w;  w += (size_t)N * 4;

  const int nb = (N + SCAN_B - 1) / SCAN_B;   // 157 <= 256, single-block aux scan ok

  k_zero_int  <<<(N + 255) / 256, 256, 0, stream>>>(deg, N);
  k_degree    <<<(E + 255) / 256, 256, 0, stream>>>(dst, E, deg);
  k_scan_local<<<nb, SCAN_B, 0, stream>>>(deg, N, off, aux);
  k_scan_aux  <<<1, SCAN_B, 0, stream>>>(aux, nb);
  k_finish    <<<nb, SCAN_B, 0, stream>>>(off, aux, deg, dinv, curs, N, E);
  k_fill      <<<(E + 255) / 256, 256, 0, stream>>>(src, dst, E, curs, csr);

  const int gemm_blocks = (N + 63) / 64;
  k_gemm_scaled<<<gemm_blocks, 256, 0, stream>>>(x, W1, dinv, xw, N);
  k_prop       <<<(N + 7) / 8, 256, 0, stream>>>((const float4*)xw, off, csr, dinv,
                                                 (const float4*)b1, (float4*)h, N);
  k_gemm_scaled<<<gemm_blocks, 256, 0, stream>>>(h, W2, dinv, xw, N);
  k_prop       <<<(N + 7) / 8, 256, 0, stream>>>((const float4*)xw, off, csr, dinv,
                                                 (const float4*)b2, (float4*)h, N);

  k_pool<<<G, 256, 0, stream>>>((const float4*)h, batch, N, (float4*)d_out);
}

// Round 3
// 332.984 us; speedup vs baseline: 9.5690x; 9.5690x over previous
//
#include <hip/hip_runtime.h>

static constexpr int FEAT = 128;
static constexpr int SCAN_B = 256;

__device__ __forceinline__ float4 f4add(float4 a, float4 b) {
  return make_float4(a.x + b.x, a.y + b.y, a.z + b.z, a.w + b.w);
}

// ---------------- CSR build ----------------

__global__ void k_zero_int(int* __restrict__ p, int n) {
  int i = blockIdx.x * blockDim.x + threadIdx.x;
  if (i < n) p[i] = 0;
}

__global__ void k_degree(const int* __restrict__ dst, int E, int* __restrict__ deg) {
  int e = blockIdx.x * blockDim.x + threadIdx.x;
  if (e < E) atomicAdd(&deg[dst[e]], 1);
}

__global__ void k_scan_local(const int* __restrict__ deg, int N,
                             int* __restrict__ off, int* __restrict__ aux) {
  __shared__ int s[SCAN_B];
  int t = threadIdx.x;
  int i = blockIdx.x * SCAN_B + t;
  int v = (i < N) ? deg[i] : 0;
  s[t] = v;
  __syncthreads();
  for (int d = 1; d < SCAN_B; d <<= 1) {
    int add = (t >= d) ? s[t - d] : 0;
    __syncthreads();
    s[t] += add;
    __syncthreads();
  }
  if (i < N) off[i] = s[t] - v;            // exclusive within block
  if (t == SCAN_B - 1) aux[blockIdx.x] = s[t];
}

__global__ void k_scan_aux(int* __restrict__ aux, int nb) {
  __shared__ int s[SCAN_B];
  int t = threadIdx.x;
  int v = (t < nb) ? aux[t] : 0;
  s[t] = v;
  __syncthreads();
  for (int d = 1; d < SCAN_B; d <<= 1) {
    int add = (t >= d) ? s[t - d] : 0;
    __syncthreads();
    s[t] += add;
    __syncthreads();
  }
  if (t < nb) aux[t] = s[t] - v;           // exclusive block offsets
}

__global__ void k_finish(int* __restrict__ off, const int* __restrict__ aux,
                         const int* __restrict__ deg, float* __restrict__ dinv,
                         int* __restrict__ cursor, int N, int E) {
  int i = blockIdx.x * blockDim.x + threadIdx.x;
  if (i < N) {
    int o = off[i] + aux[i >> 8];          // blockDim == SCAN_B == 256
    off[i] = o;
    cursor[i] = o;
    dinv[i] = rsqrtf((float)(deg[i] + 1)); // degree over A+I
  }
  if (i == 0) off[N] = E;
}

__global__ void k_fill(const int* __restrict__ src, const int* __restrict__ dst, int E,
                       int* __restrict__ cursor, int* __restrict__ csr) {
  int e = blockIdx.x * blockDim.x + threadIdx.x;
  if (e < E) {
    int p = atomicAdd(&cursor[dst[e]], 1);
    csr[p] = src[e];
  }
}

// ---------------- dense GEMM: Y[r] = dinv[r] * (X[r] @ W) ----------------
// Whole W resident in LDS (64 KiB, staged once, no double-buffer, no transpose
// -> minimal register liveness; round-2's staging pipeline spilled to scratch).
// 128x128 C-tile per block; per-thread 8 rows x 8 cols. Per k-step per wave:
// 2 ds_read_b128 (~24 cyc) vs 64 FMA (128 cyc) -> VALU-bound.
__global__ __launch_bounds__(256) void k_gemm_scaled(
    const float* __restrict__ X, const float* __restrict__ W,
    const float* __restrict__ dinv, float* __restrict__ Y, int N) {
  __shared__ float ws[FEAT * FEAT];        // 65536 bytes
  {
    const float4* W4 = (const float4*)W;
    float4* ws4 = (float4*)ws;
    for (int i = threadIdx.x; i < FEAT * FEAT / 4; i += 256) ws4[i] = W4[i];
  }
  __syncthreads();

  const int t = threadIdx.x;
  const int ct = t & 15;                   // cols ct*8 .. ct*8+7
  const int rt = t >> 4;                   // row group: 8 rows
  const int r0 = blockIdx.x * 128 + rt * 8;
  if (r0 >= N) return;

  // per-row base pointers (clamped; duplicate work beyond N is discarded)
  const float* xr[8];
#pragma unroll
  for (int i = 0; i < 8; i++) {
    int r = r0 + i;
    xr[i] = X + (size_t)(r < N ? r : N - 1) * FEAT;
  }

  float acc[8][8];
#pragma unroll
  for (int i = 0; i < 8; i++)
#pragma unroll
    for (int j = 0; j < 8; j++) acc[i][j] = 0.f;

  for (int k = 0; k < FEAT; k += 4) {      // dynamic outer loop bounds liveness
    float4 xq[8];
#pragma unroll
    for (int i = 0; i < 8; i++) xq[i] = *(const float4*)(xr[i] + k);
#pragma unroll
    for (int kk = 0; kk < 4; kk++) {
      const float* wr = ws + (k + kk) * FEAT + ct * 8;
      float4 w0 = *(const float4*)(wr);
      float4 w1 = *(const float4*)(wr + 4);
      float wx[8] = {w0.x, w0.y, w0.z, w0.w, w1.x, w1.y, w1.z, w1.w};
#pragma unroll
      for (int i = 0; i < 8; i++) {
        float xv = (kk == 0) ? xq[i].x : (kk == 1) ? xq[i].y : (kk == 2) ? xq[i].z : xq[i].w;
#pragma unroll
        for (int j = 0; j < 8; j++) acc[i][j] += xv * wx[j];
      }
    }
  }

  // epilogue: scale rows by dinv, store
#pragma unroll
  for (int i = 0; i < 8; i++) {
    const int r = r0 + i;
    if (r >= N) break;
    const float dn = dinv[r];
    float4 o0 = make_float4(acc[i][0] * dn, acc[i][1] * dn, acc[i][2] * dn, acc[i][3] * dn);
    float4 o1 = make_float4(acc[i][4] * dn, acc[i][5] * dn, acc[i][6] * dn, acc[i][7] * dn);
    float4* yp = (float4*)(Y + (size_t)r * FEAT + ct * 8);
    yp[0] = o0;
    yp[1] = o1;
  }
}

// ---------------- propagation ----------------
// h[n] = relu(dinv[n]*(sum_in xws[s] + xws[n]) + b), xws pre-scaled by dinv.
// 32 lanes x float4 per node, 8 nodes/block, edge loop unrolled x4 (4 gathers in flight).
__global__ __launch_bounds__(256) void k_prop(
    const float4* __restrict__ X4, const int* __restrict__ off,
    const int* __restrict__ csr, const float* __restrict__ dinv,
    const float4* __restrict__ bias4, float4* __restrict__ H4, int N) {
  const int node = blockIdx.x * 8 + (threadIdx.x >> 5);
  if (node >= N) return;
  const int j = threadIdx.x & 31;
  const int i0 = off[node], i1 = off[node + 1];
  float4 a0 = make_float4(0.f, 0.f, 0.f, 0.f), a1 = a0, a2 = a0, a3 = a0;
  int i = i0;
  for (; i + 4 <= i1; i += 4) {
    const int s0 = csr[i], s1 = csr[i + 1], s2 = csr[i + 2], s3 = csr[i + 3];
    float4 v0 = X4[(size_t)s0 * 32 + j];
    float4 v1 = X4[(size_t)s1 * 32 + j];
    float4 v2 = X4[(size_t)s2 * 32 + j];
    float4 v3 = X4[(size_t)s3 * 32 + j];
    a0 = f4add(a0, v0); a1 = f4add(a1, v1); a2 = f4add(a2, v2); a3 = f4add(a3, v3);
  }
  for (; i < i1; i++) a0 = f4add(a0, X4[(size_t)csr[i] * 32 + j]);
  float4 acc = f4add(f4add(a0, a1), f4add(a2, a3));
  acc = f4add(acc, X4[(size_t)node * 32 + j]);
  const float dn = dinv[node];
  const float4 b = bias4[j];
  float4 r;
  r.x = fmaxf(dn * acc.x + b.x, 0.f);
  r.y = fmaxf(dn * acc.y + b.y, 0.f);
  r.z = fmaxf(dn * acc.z + b.z, 0.f);
  r.w = fmaxf(dn * acc.w + b.w, 0.f);
  H4[(size_t)node * 32 + j] = r;
}

// ---------------- pooling: per-graph mean over sorted batch ----------------
__device__ __forceinline__ int lower_bound(const int* __restrict__ a, int n, int v) {
  int lo = 0, hi = n;
  while (lo < hi) { int m = (lo + hi) >> 1; if (a[m] < v) lo = m + 1; else hi = m; }
  return lo;
}

__global__ __launch_bounds__(256) void k_pool(
    const float4* __restrict__ H4, const int* __restrict__ batch,
    int N, float4* __restrict__ out4) {
  __shared__ float4 red[8][32];
  const int g = blockIdx.x;
  const int grp = threadIdx.x >> 5;
  const int j = threadIdx.x & 31;
  const int lo = lower_bound(batch, N, g);
  const int hi = lower_bound(batch, N, g + 1);
  float4 a = make_float4(0.f, 0.f, 0.f, 0.f);
  for (int r = lo + grp; r < hi; r += 8) a = f4add(a, H4[(size_t)r * 32 + j]);
  red[grp][j] = a;
  __syncthreads();
  if (grp == 0) {
    float4 s = red[0][j];
#pragma unroll
    for (int k = 1; k < 8; k++) s = f4add(s, red[k][j]);
    const int cnt = hi - lo;
    const float dn = 1.0f / (float)(cnt > 1 ? cnt : 1);
    out4[g * 32 + j] = make_float4(s.x * dn, s.y * dn, s.z * dn, s.w * dn);
  }
}

// ---------------- launch ----------------
extern "C" void kernel_launch(void* const* d_in, const int* in_sizes, int n_in,
                              void* d_out, int out_size, void* d_ws, size_t ws_size,
                              hipStream_t stream) {
  const float* x     = (const float*)d_in[0];
  const int*   ei    = (const int*)  d_in[1];
  const int*   batch = (const int*)  d_in[2];
  // d_in[3] = num_graphs scalar (derived from out_size instead)
  const float* W1    = (const float*)d_in[4];
  const float* b1    = (const float*)d_in[5];
  const float* W2    = (const float*)d_in[6];
  const float* b2    = (const float*)d_in[7];

  const int N = in_sizes[0] / FEAT;
  const int E = in_sizes[1] / 2;
  const int G = out_size / FEAT;
  const int* src = ei;
  const int* dst = ei + E;

  char* w = (char*)d_ws;
  float* xw   = (float*)w;  w += (size_t)N * FEAT * 4;
  float* h    = (float*)w;  w += (size_t)N * FEAT * 4;
  int*   deg  = (int*)w;    w += (size_t)N * 4;
  int*   off  = (int*)w;    w += ((size_t)(N + 1) * 4 + 15) & ~(size_t)15;
  int*   aux  = (int*)w;    w += 256 * 4;
  int*   curs = (int*)w;    w += (size_t)N * 4;
  int*   csr  = (int*)w;    w += (size_t)E * 4;
  float* dinv = (float*)w;  w += (size_t)N * 4;

  const int nb = (N + SCAN_B - 1) / SCAN_B;   // 157 <= 256, single-block aux scan ok

  k_zero_int  <<<(N + 255) / 256, 256, 0, stream>>>(deg, N);
  k_degree    <<<(E + 255) / 256, 256, 0, stream>>>(dst, E, deg);
  k_scan_local<<<nb, SCAN_B, 0, stream>>>(deg, N, off, aux);
  k_scan_aux  <<<1, SCAN_B, 0, stream>>>(aux, nb);
  k_finish    <<<nb, SCAN_B, 0, stream>>>(off, aux, deg, dinv, curs, N, E);
  k_fill      <<<(E + 255) / 256, 256, 0, stream>>>(src, dst, E, curs, csr);

  const int gemm_blocks = (N + 127) / 128;
  k_gemm_scaled<<<gemm_blocks, 256, 0, stream>>>(x, W1, dinv, xw, N);
  k_prop       <<<(N + 7) / 8, 256, 0, stream>>>((const float4*)xw, off, csr, dinv,
                                                 (const float4*)b1, (float4*)h, N);
  k_gemm_scaled<<<gemm_blocks, 256, 0, stream>>>(h, W2, dinv, xw, N);
  k_prop       <<<(N + 7) / 8, 256, 0, stream>>>((const float4*)xw, off, csr, dinv,
                                                 (const float4*)b2, (float4*)h, N);

  k_pool<<<G, 256, 0, stream>>>((const float4*)h, batch, N, (float4*)d_out);
}

// Round 4
// 298.322 us; speedup vs baseline: 10.6808x; 1.1162x over previous
//
#include <hip/hip_runtime.h>

static constexpr int FEAT = 128;
static constexpr int SCAN_B = 256;

__device__ __forceinline__ float4 f4add(float4 a, float4 b) {
  return make_float4(a.x + b.x, a.y + b.y, a.z + b.z, a.w + b.w);
}
__device__ __forceinline__ float bf2f(unsigned short u) {
  union { unsigned int i; float f; } v; v.i = ((unsigned int)u) << 16; return v.f;
}
__device__ __forceinline__ unsigned short f2bf(float f) {
  union { float f; unsigned int i; } v; v.f = f;
  unsigned int r = v.i + 0x7FFFu + ((v.i >> 16) & 1u);  // RNE
  return (unsigned short)(r >> 16);
}
__device__ __forceinline__ float4 us4_to_f4(ushort4 q) {
  return make_float4(bf2f(q.x), bf2f(q.y), bf2f(q.z), bf2f(q.w));
}
__device__ __forceinline__ ushort4 f4_to_us4(float4 a) {
  ushort4 q; q.x = f2bf(a.x); q.y = f2bf(a.y); q.z = f2bf(a.z); q.w = f2bf(a.w);
  return q;
}

// ---------------- CSR build ----------------

__global__ void k_zero_int(int* __restrict__ p, int n) {
  int i = blockIdx.x * blockDim.x + threadIdx.x;
  if (i < n) p[i] = 0;
}

__global__ void k_degree(const int* __restrict__ dst, int E, int* __restrict__ deg) {
  int e = blockIdx.x * blockDim.x + threadIdx.x;
  if (e < E) atomicAdd(&deg[dst[e]], 1);
}

__global__ void k_scan_local(const int* __restrict__ deg, int N,
                             int* __restrict__ off, int* __restrict__ aux) {
  __shared__ int s[SCAN_B];
  int t = threadIdx.x;
  int i = blockIdx.x * SCAN_B + t;
  int v = (i < N) ? deg[i] : 0;
  s[t] = v;
  __syncthreads();
  for (int d = 1; d < SCAN_B; d <<= 1) {
    int add = (t >= d) ? s[t - d] : 0;
    __syncthreads();
    s[t] += add;
    __syncthreads();
  }
  if (i < N) off[i] = s[t] - v;            // exclusive within block
  if (t == SCAN_B - 1) aux[blockIdx.x] = s[t];
}

__global__ void k_scan_aux(int* __restrict__ aux, int nb) {
  __shared__ int s[SCAN_B];
  int t = threadIdx.x;
  int v = (t < nb) ? aux[t] : 0;
  s[t] = v;
  __syncthreads();
  for (int d = 1; d < SCAN_B; d <<= 1) {
    int add = (t >= d) ? s[t - d] : 0;
    __syncthreads();
    s[t] += add;
    __syncthreads();
  }
  if (t < nb) aux[t] = s[t] - v;           // exclusive block offsets
}

__global__ void k_finish(int* __restrict__ off, const int* __restrict__ aux,
                         const int* __restrict__ deg, float* __restrict__ dinv,
                         int* __restrict__ cursor, int N, int E) {
  int i = blockIdx.x * blockDim.x + threadIdx.x;
  if (i < N) {
    int o = off[i] + aux[i >> 8];          // blockDim == SCAN_B == 256
    off[i] = o;
    cursor[i] = o;
    dinv[i] = rsqrtf((float)(deg[i] + 1)); // degree over A+I
  }
  if (i == 0) off[N] = E;
}

__global__ void k_fill(const int* __restrict__ src, const int* __restrict__ dst, int E,
                       int* __restrict__ cursor, int* __restrict__ csr) {
  int e = blockIdx.x * blockDim.x + threadIdx.x;
  if (e < E) {
    int p = atomicAdd(&cursor[dst[e]], 1);
    csr[p] = src[e];
  }
}

// ---------------- dense GEMM: Ybf[r] = bf16( dinv[r] * (X[r] @ W) ) -------
// Whole W (f32) resident in LDS; 128x128 C-tile/block; 8x8 per-thread tile.
// Templated on input dtype: float (layer 1) or bf16-as-ushort (layer 2).
template <typename T>
__device__ __forceinline__ float4 load_row4(const T* p);
template <>
__device__ __forceinline__ float4 load_row4<float>(const float* p) {
  return *(const float4*)p;
}
template <>
__device__ __forceinline__ float4 load_row4<unsigned short>(const unsigned short* p) {
  return us4_to_f4(*(const ushort4*)p);
}

template <typename T>
__global__ __launch_bounds__(256) void k_gemm_scaled(
    const T* __restrict__ X, const float* __restrict__ W,
    const float* __restrict__ dinv, unsigned short* __restrict__ Ybf, int N) {
  __shared__ float ws[FEAT * FEAT];        // 65536 bytes
  {
    const float4* W4 = (const float4*)W;
    float4* ws4 = (float4*)ws;
    for (int i = threadIdx.x; i < FEAT * FEAT / 4; i += 256) ws4[i] = W4[i];
  }
  __syncthreads();

  const int t = threadIdx.x;
  const int ct = t & 15;                   // cols ct*8 .. ct*8+7
  const int rt = t >> 4;                   // row group: 8 rows
  const int r0 = blockIdx.x * 128 + rt * 8;
  if (r0 >= N) return;

  const T* xr[8];
#pragma unroll
  for (int i = 0; i < 8; i++) {
    int r = r0 + i;
    xr[i] = X + (size_t)(r < N ? r : N - 1) * FEAT;
  }

  float acc[8][8];
#pragma unroll
  for (int i = 0; i < 8; i++)
#pragma unroll
    for (int j = 0; j < 8; j++) acc[i][j] = 0.f;

  for (int k = 0; k < FEAT; k += 4) {      // dynamic outer loop bounds liveness
    float4 xq[8];
#pragma unroll
    for (int i = 0; i < 8; i++) xq[i] = load_row4<T>(xr[i] + k);
#pragma unroll
    for (int kk = 0; kk < 4; kk++) {
      const float* wr = ws + (k + kk) * FEAT + ct * 8;
      float4 w0 = *(const float4*)(wr);
      float4 w1 = *(const float4*)(wr + 4);
      float wx[8] = {w0.x, w0.y, w0.z, w0.w, w1.x, w1.y, w1.z, w1.w};
#pragma unroll
      for (int i = 0; i < 8; i++) {
        float xv = (kk == 0) ? xq[i].x : (kk == 1) ? xq[i].y : (kk == 2) ? xq[i].z : xq[i].w;
#pragma unroll
        for (int j = 0; j < 8; j++) acc[i][j] += xv * wx[j];
      }
    }
  }

#pragma unroll
  for (int i = 0; i < 8; i++) {
    const int r = r0 + i;
    if (r >= N) break;
    const float dn = dinv[r];
    float4 o0 = make_float4(acc[i][0] * dn, acc[i][1] * dn, acc[i][2] * dn, acc[i][3] * dn);
    float4 o1 = make_float4(acc[i][4] * dn, acc[i][5] * dn, acc[i][6] * dn, acc[i][7] * dn);
    ushort4* yp = (ushort4*)(Ybf + (size_t)r * FEAT + ct * 8);
    yp[0] = f4_to_us4(o0);
    yp[1] = f4_to_us4(o1);
  }
}

// ---------------- propagation (bf16 rows) ----------------
// h[n] = relu(dinv[n]*(sum_in xws[s] + xws[n]) + b), xws pre-scaled by dinv.
// Rows are 128 bf16 = 256 B: 32 lanes x ushort4 (8 B). 8 nodes/block.
// Edge loop unrolled x4 -> 4 row-gathers in flight per node.
__global__ __launch_bounds__(256) void k_prop(
    const ushort4* __restrict__ X4, const int* __restrict__ off,
    const int* __restrict__ csr, const float* __restrict__ dinv,
    const float4* __restrict__ bias4, ushort4* __restrict__ H4, int N) {
  const int node = blockIdx.x * 8 + (threadIdx.x >> 5);
  if (node >= N) return;
  const int j = threadIdx.x & 31;
  const int i0 = off[node], i1 = off[node + 1];
  float4 a0 = make_float4(0.f, 0.f, 0.f, 0.f), a1 = a0, a2 = a0, a3 = a0;
  int i = i0;
  for (; i + 4 <= i1; i += 4) {
    const int s0 = csr[i], s1 = csr[i + 1], s2 = csr[i + 2], s3 = csr[i + 3];
    ushort4 v0 = X4[(size_t)s0 * 32 + j];
    ushort4 v1 = X4[(size_t)s1 * 32 + j];
    ushort4 v2 = X4[(size_t)s2 * 32 + j];
    ushort4 v3 = X4[(size_t)s3 * 32 + j];
    a0 = f4add(a0, us4_to_f4(v0));
    a1 = f4add(a1, us4_to_f4(v1));
    a2 = f4add(a2, us4_to_f4(v2));
    a3 = f4add(a3, us4_to_f4(v3));
  }
  for (; i < i1; i++) a0 = f4add(a0, us4_to_f4(X4[(size_t)csr[i] * 32 + j]));
  float4 acc = f4add(f4add(a0, a1), f4add(a2, a3));
  acc = f4add(acc, us4_to_f4(X4[(size_t)node * 32 + j]));
  const float dn = dinv[node];
  const float4 b = bias4[j];
  float4 r;
  r.x = fmaxf(dn * acc.x + b.x, 0.f);
  r.y = fmaxf(dn * acc.y + b.y, 0.f);
  r.z = fmaxf(dn * acc.z + b.z, 0.f);
  r.w = fmaxf(dn * acc.w + b.w, 0.f);
  H4[(size_t)node * 32 + j] = f4_to_us4(r);
}

// ---------------- pooling: per-graph mean over sorted batch ----------------
__device__ __forceinline__ int lower_bound(const int* __restrict__ a, int n, int v) {
  int lo = 0, hi = n;
  while (lo < hi) { int m = (lo + hi) >> 1; if (a[m] < v) lo = m + 1; else hi = m; }
  return lo;
}

__global__ __launch_bounds__(256) void k_pool(
    const ushort4* __restrict__ H4, const int* __restrict__ batch,
    int N, float4* __restrict__ out4) {
  __shared__ float4 red[8][32];
  const int g = blockIdx.x;
  const int grp = threadIdx.x >> 5;
  const int j = threadIdx.x & 31;
  const int lo = lower_bound(batch, N, g);
  const int hi = lower_bound(batch, N, g + 1);
  float4 a = make_float4(0.f, 0.f, 0.f, 0.f);
  for (int r = lo + grp; r < hi; r += 8) a = f4add(a, us4_to_f4(H4[(size_t)r * 32 + j]));
  red[grp][j] = a;
  __syncthreads();
  if (grp == 0) {
    float4 s = red[0][j];
#pragma unroll
    for (int k = 1; k < 8; k++) s = f4add(s, red[k][j]);
    const int cnt = hi - lo;
    const float dn = 1.0f / (float)(cnt > 1 ? cnt : 1);
    out4[g * 32 + j] = make_float4(s.x * dn, s.y * dn, s.z * dn, s.w * dn);
  }
}

// ---------------- launch ----------------
extern "C" void kernel_launch(void* const* d_in, const int* in_sizes, int n_in,
                              void* d_out, int out_size, void* d_ws, size_t ws_size,
                              hipStream_t stream) {
  const float* x     = (const float*)d_in[0];
  const int*   ei    = (const int*)  d_in[1];
  const int*   batch = (const int*)  d_in[2];
  // d_in[3] = num_graphs scalar (derived from out_size instead)
  const float* W1    = (const float*)d_in[4];
  const float* b1    = (const float*)d_in[5];
  const float* W2    = (const float*)d_in[6];
  const float* b2    = (const float*)d_in[7];

  const int N = in_sizes[0] / FEAT;
  const int E = in_sizes[1] / 2;
  const int G = out_size / FEAT;
  const int* src = ei;
  const int* dst = ei + E;

  char* w = (char*)d_ws;
  unsigned short* xw = (unsigned short*)w;  w += ((size_t)N * FEAT * 2 + 15) & ~(size_t)15;
  unsigned short* h  = (unsigned short*)w;  w += ((size_t)N * FEAT * 2 + 15) & ~(size_t)15;
  int*   deg  = (int*)w;    w += (size_t)N * 4;
  int*   off  = (int*)w;    w += ((size_t)(N + 1) * 4 + 15) & ~(size_t)15;
  int*   aux  = (int*)w;    w += 256 * 4;
  int*   curs = (int*)w;    w += (size_t)N * 4;
  int*   csr  = (int*)w;    w += (size_t)E * 4;
  float* dinv = (float*)w;  w += (size_t)N * 4;

  const int nb = (N + SCAN_B - 1) / SCAN_B;   // 157 <= 256, single-block aux scan ok

  k_zero_int  <<<(N + 255) / 256, 256, 0, stream>>>(deg, N);
  k_degree    <<<(E + 255) / 256, 256, 0, stream>>>(dst, E, deg);
  k_scan_local<<<nb, SCAN_B, 0, stream>>>(deg, N, off, aux);
  k_scan_aux  <<<1, SCAN_B, 0, stream>>>(aux, nb);
  k_finish    <<<nb, SCAN_B, 0, stream>>>(off, aux, deg, dinv, curs, N, E);
  k_fill      <<<(E + 255) / 256, 256, 0, stream>>>(src, dst, E, curs, csr);

  const int gemm_blocks = (N + 127) / 128;
  k_gemm_scaled<float><<<gemm_blocks, 256, 0, stream>>>(x, W1, dinv, xw, N);
  k_prop<<<(N + 7) / 8, 256, 0, stream>>>((const ushort4*)xw, off, csr, dinv,
                                          (const float4*)b1, (ushort4*)h, N);
  k_gemm_scaled<unsigned short><<<gemm_blocks, 256, 0, stream>>>(h, W2, dinv, xw, N);
  k_prop<<<(N + 7) / 8, 256, 0, stream>>>((const ushort4*)xw, off, csr, dinv,
                                          (const float4*)b2, (ushort4*)h, N);

  k_pool<<<G, 256, 0, stream>>>((const ushort4*)h, batch, N, (float4*)d_out);
}

// Round 5
// 278.543 us; speedup vs baseline: 11.4392x; 1.0710x over previous
//
#include <hip/hip_runtime.h>

static constexpr int FEAT = 128;
static constexpr int SCAN_B = 256;

__device__ __forceinline__ float4 f4add(float4 a, float4 b) {
  return make_float4(a.x + b.x, a.y + b.y, a.z + b.z, a.w + b.w);
}
__device__ __forceinline__ float bf2f(unsigned short u) {
  union { unsigned int i; float f; } v; v.i = ((unsigned int)u) << 16; return v.f;
}
__device__ __forceinline__ unsigned short f2bf(float f) {
  union { float f; unsigned int i; } v; v.f = f;
  unsigned int r = v.i + 0x7FFFu + ((v.i >> 16) & 1u);  // RNE
  return (unsigned short)(r >> 16);
}
__device__ __forceinline__ float4 us4_to_f4(ushort4 q) {
  return make_float4(bf2f(q.x), bf2f(q.y), bf2f(q.z), bf2f(q.w));
}
__device__ __forceinline__ ushort4 f4_to_us4(float4 a) {
  ushort4 q; q.x = f2bf(a.x); q.y = f2bf(a.y); q.z = f2bf(a.z); q.w = f2bf(a.w);
  return q;
}

// ---------------- CSR build ----------------

__global__ void k_zero_int(int* __restrict__ p, int n) {
  int i = blockIdx.x * blockDim.x + threadIdx.x;
  if (i < n) p[i] = 0;
}

__global__ void k_degree(const int* __restrict__ dst, int E, int* __restrict__ deg) {
  int e = blockIdx.x * blockDim.x + threadIdx.x;
  if (e < E) atomicAdd(&deg[dst[e]], 1);
}

__global__ void k_scan_local(const int* __restrict__ deg, int N,
                             int* __restrict__ off, int* __restrict__ aux) {
  __shared__ int s[SCAN_B];
  int t = threadIdx.x;
  int i = blockIdx.x * SCAN_B + t;
  int v = (i < N) ? deg[i] : 0;
  s[t] = v;
  __syncthreads();
  for (int d = 1; d < SCAN_B; d <<= 1) {
    int add = (t >= d) ? s[t - d] : 0;
    __syncthreads();
    s[t] += add;
    __syncthreads();
  }
  if (i < N) off[i] = s[t] - v;            // exclusive within block
  if (t == SCAN_B - 1) aux[blockIdx.x] = s[t];
}

__global__ void k_scan_aux(int* __restrict__ aux, int nb) {
  __shared__ int s[SCAN_B];
  int t = threadIdx.x;
  int v = (t < nb) ? aux[t] : 0;
  s[t] = v;
  __syncthreads();
  for (int d = 1; d < SCAN_B; d <<= 1) {
    int add = (t >= d) ? s[t - d] : 0;
    __syncthreads();
    s[t] += add;
    __syncthreads();
  }
  if (t < nb) aux[t] = s[t] - v;           // exclusive block offsets
}

__global__ void k_finish(int* __restrict__ off, const int* __restrict__ aux,
                         const int* __restrict__ deg, float* __restrict__ dinv,
                         int* __restrict__ cursor, int N, int E) {
  int i = blockIdx.x * blockDim.x + threadIdx.x;
  if (i < N) {
    int o = off[i] + aux[i >> 8];          // blockDim == SCAN_B == 256
    off[i] = o;
    cursor[i] = o;
    dinv[i] = rsqrtf((float)(deg[i] + 1)); // degree over A+I
  }
  if (i == 0) off[N] = E;
}

__global__ void k_fill(const int* __restrict__ src, const int* __restrict__ dst, int E,
                       int* __restrict__ cursor, int* __restrict__ csr) {
  int e = blockIdx.x * blockDim.x + threadIdx.x;
  if (e < E) {
    int p = atomicAdd(&cursor[dst[e]], 1);
    csr[p] = src[e];
  }
}

// ---------------- dense GEMM: Ybf[r] = bf16( dinv[r] * (X[r] @ W) ) -------
// 64-row tile/block (625 blocks: balanced across 256 CUs). W staged in two
// 32 KiB halves through ONE reused LDS buffer -> 5 blocks/CU resident.
// Per-thread 4 rows x 8 cols; cols split [ct*4, ct*4+64] so the wave's 16
// distinct ds_read_b128 addresses cover all 8 bank-groups (2-way = free;
// round-4's ct*8 mapping was 4-way = 1.58x tax, 1.28M conflicts).
template <typename T>
__device__ __forceinline__ float4 load_row4(const T* p);
template <>
__device__ __forceinline__ float4 load_row4<float>(const float* p) {
  return *(const float4*)p;
}
template <>
__device__ __forceinline__ float4 load_row4<unsigned short>(const unsigned short* p) {
  return us4_to_f4(*(const ushort4*)p);
}

template <typename T>
__global__ __launch_bounds__(256) void k_gemm_scaled(
    const T* __restrict__ X, const float* __restrict__ W,
    const float* __restrict__ dinv, unsigned short* __restrict__ Ybf, int N) {
  __shared__ float ws[64 * FEAT];          // 32768 bytes, reused for both K-halves

  const int t = threadIdx.x;
  const int ct = t & 15;                   // col groups: ct*4 and ct*4+64
  const int rt = t >> 4;                   // row group: 4 rows
  const int r0 = blockIdx.x * 64 + rt * 4;

  const T* xr[4];
#pragma unroll
  for (int i = 0; i < 4; i++) {
    int r = r0 + i;
    xr[i] = X + (size_t)(r < N ? r : (N > 0 ? N - 1 : 0)) * FEAT;
  }

  float acc[4][8];
#pragma unroll
  for (int i = 0; i < 4; i++)
#pragma unroll
    for (int j = 0; j < 8; j++) acc[i][j] = 0.f;

  for (int s = 0; s < 2; s++) {            // two K-halves of 64
    // stage W[s*64 .. s*64+63][*] into LDS (contiguous: 2-way bank = free)
    if (s) __syncthreads();                // all reads of previous half done
    {
      const float4* W4 = (const float4*)(W + (size_t)s * 64 * FEAT);
      float4* ws4 = (float4*)ws;
#pragma unroll
      for (int i = 0; i < 8; i++) ws4[t + i * 256] = W4[t + i * 256];
    }
    __syncthreads();

    const int kbase = s * 64;
    for (int k4 = 0; k4 < 64; k4 += 4) {
      float4 xq[4];
#pragma unroll
      for (int i = 0; i < 4; i++) xq[i] = load_row4<T>(xr[i] + kbase + k4);
#pragma unroll
      for (int kk = 0; kk < 4; kk++) {
        const float* wr = ws + (k4 + kk) * FEAT + ct * 4;
        float4 wa = *(const float4*)(wr);
        float4 wb = *(const float4*)(wr + 64);
        float wx[8] = {wa.x, wa.y, wa.z, wa.w, wb.x, wb.y, wb.z, wb.w};
#pragma unroll
        for (int i = 0; i < 4; i++) {
          float xv = (kk == 0) ? xq[i].x : (kk == 1) ? xq[i].y : (kk == 2) ? xq[i].z : xq[i].w;
#pragma unroll
          for (int j = 0; j < 8; j++) acc[i][j] += xv * wx[j];
        }
      }
    }
  }

#pragma unroll
  for (int i = 0; i < 4; i++) {
    const int r = r0 + i;
    if (r >= N) break;
    const float dn = dinv[r];
    float4 o0 = make_float4(acc[i][0] * dn, acc[i][1] * dn, acc[i][2] * dn, acc[i][3] * dn);
    float4 o1 = make_float4(acc[i][4] * dn, acc[i][5] * dn, acc[i][6] * dn, acc[i][7] * dn);
    *(ushort4*)(Ybf + (size_t)r * FEAT + ct * 4)      = f4_to_us4(o0);
    *(ushort4*)(Ybf + (size_t)r * FEAT + ct * 4 + 64) = f4_to_us4(o1);
  }
}

// ---------------- propagation (bf16 rows) ----------------
// h[n] = relu(dinv[n]*(sum_in xws[s] + xws[n]) + b), xws pre-scaled by dinv.
// Rows are 128 bf16 = 256 B: 32 lanes x ushort4. 8 nodes/block.
// Edge loop unrolled x8 -> 8 row-gathers in flight per node.
__global__ __launch_bounds__(256) void k_prop(
    const ushort4* __restrict__ X4, const int* __restrict__ off,
    const int* __restrict__ csr, const float* __restrict__ dinv,
    const float4* __restrict__ bias4, ushort4* __restrict__ H4, int N) {
  const int node = blockIdx.x * 8 + (threadIdx.x >> 5);
  if (node >= N) return;
  const int j = threadIdx.x & 31;
  const int i0 = off[node], i1 = off[node + 1];
  float4 a0 = make_float4(0.f, 0.f, 0.f, 0.f), a1 = a0, a2 = a0, a3 = a0;
  int i = i0;
  for (; i + 8 <= i1; i += 8) {
    const int s0 = csr[i],     s1 = csr[i + 1], s2 = csr[i + 2], s3 = csr[i + 3];
    const int s4 = csr[i + 4], s5 = csr[i + 5], s6 = csr[i + 6], s7 = csr[i + 7];
    ushort4 v0 = X4[(size_t)s0 * 32 + j];
    ushort4 v1 = X4[(size_t)s1 * 32 + j];
    ushort4 v2 = X4[(size_t)s2 * 32 + j];
    ushort4 v3 = X4[(size_t)s3 * 32 + j];
    ushort4 v4 = X4[(size_t)s4 * 32 + j];
    ushort4 v5 = X4[(size_t)s5 * 32 + j];
    ushort4 v6 = X4[(size_t)s6 * 32 + j];
    ushort4 v7 = X4[(size_t)s7 * 32 + j];
    a0 = f4add(a0, us4_to_f4(v0)); a1 = f4add(a1, us4_to_f4(v1));
    a2 = f4add(a2, us4_to_f4(v2)); a3 = f4add(a3, us4_to_f4(v3));
    a0 = f4add(a0, us4_to_f4(v4)); a1 = f4add(a1, us4_to_f4(v5));
    a2 = f4add(a2, us4_to_f4(v6)); a3 = f4add(a3, us4_to_f4(v7));
  }
  for (; i + 4 <= i1; i += 4) {
    const int s0 = csr[i], s1 = csr[i + 1], s2 = csr[i + 2], s3 = csr[i + 3];
    ushort4 v0 = X4[(size_t)s0 * 32 + j];
    ushort4 v1 = X4[(size_t)s1 * 32 + j];
    ushort4 v2 = X4[(size_t)s2 * 32 + j];
    ushort4 v3 = X4[(size_t)s3 * 32 + j];
    a0 = f4add(a0, us4_to_f4(v0)); a1 = f4add(a1, us4_to_f4(v1));
    a2 = f4add(a2, us4_to_f4(v2)); a3 = f4add(a3, us4_to_f4(v3));
  }
  for (; i < i1; i++) a0 = f4add(a0, us4_to_f4(X4[(size_t)csr[i] * 32 + j]));
  float4 acc = f4add(f4add(a0, a1), f4add(a2, a3));
  acc = f4add(acc, us4_to_f4(X4[(size_t)node * 32 + j]));
  const float dn = dinv[node];
  const float4 b = bias4[j];
  float4 r;
  r.x = fmaxf(dn * acc.x + b.x, 0.f);
  r.y = fmaxf(dn * acc.y + b.y, 0.f);
  r.z = fmaxf(dn * acc.z + b.z, 0.f);
  r.w = fmaxf(dn * acc.w + b.w, 0.f);
  H4[(size_t)node * 32 + j] = f4_to_us4(r);
}

// ---------------- pooling: per-graph mean over sorted batch ----------------
__device__ __forceinline__ int lower_bound(const int* __restrict__ a, int n, int v) {
  int lo = 0, hi = n;
  while (lo < hi) { int m = (lo + hi) >> 1; if (a[m] < v) lo = m + 1; else hi = m; }
  return lo;
}

__global__ __launch_bounds__(256) void k_pool(
    const ushort4* __restrict__ H4, const int* __restrict__ batch,
    int N, float4* __restrict__ out4) {
  __shared__ float4 red[8][32];
  const int g = blockIdx.x;
  const int grp = threadIdx.x >> 5;
  const int j = threadIdx.x & 31;
  const int lo = lower_bound(batch, N, g);
  const int hi = lower_bound(batch, N, g + 1);
  float4 a = make_float4(0.f, 0.f, 0.f, 0.f);
  for (int r = lo + grp; r < hi; r += 8) a = f4add(a, us4_to_f4(H4[(size_t)r * 32 + j]));
  red[grp][j] = a;
  __syncthreads();
  if (grp == 0) {
    float4 s = red[0][j];
#pragma unroll
    for (int k = 1; k < 8; k++) s = f4add(s, red[k][j]);
    const int cnt = hi - lo;
    const float dn = 1.0f / (float)(cnt > 1 ? cnt : 1);
    out4[g * 32 + j] = make_float4(s.x * dn, s.y * dn, s.z * dn, s.w * dn);
  }
}

// ---------------- launch ----------------
extern "C" void kernel_launch(void* const* d_in, const int* in_sizes, int n_in,
                              void* d_out, int out_size, void* d_ws, size_t ws_size,
                              hipStream_t stream) {
  const float* x     = (const float*)d_in[0];
  const int*   ei    = (const int*)  d_in[1];
  const int*   batch = (const int*)  d_in[2];
  // d_in[3] = num_graphs scalar (derived from out_size instead)
  const float* W1    = (const float*)d_in[4];
  const float* b1    = (const float*)d_in[5];
  const float* W2    = (const float*)d_in[6];
  const float* b2    = (const float*)d_in[7];

  const int N = in_sizes[0] / FEAT;
  const int E = in_sizes[1] / 2;
  const int G = out_size / FEAT;
  const int* src = ei;
  const int* dst = ei + E;

  char* w = (char*)d_ws;
  unsigned short* xw = (unsigned short*)w;  w += ((size_t)N * FEAT * 2 + 15) & ~(size_t)15;
  unsigned short* h  = (unsigned short*)w;  w += ((size_t)N * FEAT * 2 + 15) & ~(size_t)15;
  int*   deg  = (int*)w;    w += (size_t)N * 4;
  int*   off  = (int*)w;    w += ((size_t)(N + 1) * 4 + 15) & ~(size_t)15;
  int*   aux  = (int*)w;    w += 256 * 4;
  int*   curs = (int*)w;    w += (size_t)N * 4;
  int*   csr  = (int*)w;    w += (size_t)E * 4;
  float* dinv = (float*)w;  w += (size_t)N * 4;

  const int nb = (N + SCAN_B - 1) / SCAN_B;   // 157 <= 256, single-block aux scan ok

  k_zero_int  <<<(N + 255) / 256, 256, 0, stream>>>(deg, N);
  k_degree    <<<(E + 255) / 256, 256, 0, stream>>>(dst, E, deg);
  k_scan_local<<<nb, SCAN_B, 0, stream>>>(deg, N, off, aux);
  k_scan_aux  <<<1, SCAN_B, 0, stream>>>(aux, nb);
  k_finish    <<<nb, SCAN_B, 0, stream>>>(off, aux, deg, dinv, curs, N, E);
  k_fill      <<<(E + 255) / 256, 256, 0, stream>>>(src, dst, E, curs, csr);

  const int gemm_blocks = (N + 63) / 64;
  k_gemm_scaled<float><<<gemm_blocks, 256, 0, stream>>>(x, W1, dinv, xw, N);
  k_prop<<<(N + 7) / 8, 256, 0, stream>>>((const ushort4*)xw, off, csr, dinv,
                                          (const float4*)b1, (ushort4*)h, N);
  k_gemm_scaled<unsigned short><<<gemm_blocks, 256, 0, stream>>>(h, W2, dinv, xw, N);
  k_prop<<<(N + 7) / 8, 256, 0, stream>>>((const ushort4*)xw, off, csr, dinv,
                                          (const float4*)b2, (ushort4*)h, N);

  k_pool<<<G, 256, 0, stream>>>((const ushort4*)h, batch, N, (float4*)d_out);
}